// Round 1
// baseline (4642.688 us; speedup 1.0000x reference)
//
#include <hip/hip_runtime.h>
#include <math.h>

// LLaMA-style decoder forward: B=2 S=512 D=1024 H=16 F=4096 V=32000 L=2 R=16
constexpr int B = 2, S = 512, D = 1024, H = 16, F = 4096, V = 32000, L = 2, R = 16, DH = 64;
constexpr int BS = B * S;
constexpr float LORA_SCALE = 2.0f;   // alpha/r = 32/16
constexpr float EPS = 1e-5f;

// ---------------- RoPE cache: cos/sin [S, DH] ----------------
__global__ void rope_cache_kernel(float* __restrict__ cosb, float* __restrict__ sinb) {
  int s = blockIdx.x, j = threadIdx.x;  // j in [0,32)
  // inv = 10000^(-j/32) = exp(-j/32 * ln(10000))
  float inv = __expf(-(float)j * (9.210340371976184f / 32.0f));
  float ang = (float)s * inv;
  float c = cosf(ang), sn = sinf(ang);
  cosb[s * DH + j] = c;  cosb[s * DH + j + 32] = c;
  sinb[s * DH + j] = sn; sinb[s * DH + j + 32] = sn;
}

// ---------------- Embedding gather ----------------
__global__ void embed_kernel(const int* __restrict__ ids, const float* __restrict__ emb,
                             float* __restrict__ h) {
  int row = blockIdx.x, t = threadIdx.x;  // 256 threads, D=1024 -> 4 floats each
  int id = ids[row];
  ((float4*)(h + (size_t)row * D))[t] = ((const float4*)(emb + (size_t)id * D))[t];
}

// ---------------- RMSNorm (one block per row) ----------------
__global__ void rmsnorm_kernel(const float* __restrict__ x, const float* __restrict__ w,
                               float* __restrict__ y) {
  int row = blockIdx.x, t = threadIdx.x;  // 256 threads
  float4 xv = ((const float4*)(x + (size_t)row * D))[t];
  float ss = xv.x * xv.x + xv.y * xv.y + xv.z * xv.z + xv.w * xv.w;
  __shared__ float red[256];
  red[t] = ss; __syncthreads();
  for (int s2 = 128; s2; s2 >>= 1) { if (t < s2) red[t] += red[t + s2]; __syncthreads(); }
  float rinv = rsqrtf(red[0] * (1.0f / D) + EPS);
  float4 wv = ((const float4*)w)[t];
  float4 o;
  o.x = xv.x * rinv * wv.x; o.y = xv.y * rinv * wv.y;
  o.z = xv.z * rinv * wv.z; o.w = xv.w * rinv * wv.w;
  ((float4*)(y + (size_t)row * D))[t] = o;
}

// ---------------- Generic f32 GEMM: C = [C +] scale * A[M,K] @ Bm[K,N] ----------------
template <bool ACC>
__global__ __launch_bounds__(256) void gemm_kernel(
    const float* __restrict__ A, const float* __restrict__ Bm,
    float* __restrict__ C, int M, int N, int K, float scale) {
  __shared__ float As[16][64];
  __shared__ float Bs[16][68];  // pad to soften bank conflicts
  int t = threadIdx.x;
  int tx = t & 15, ty = t >> 4;
  int m0 = blockIdx.y * 64, n0 = blockIdx.x * 64;
  float c[4][4] = {};
  for (int k0 = 0; k0 < K; k0 += 16) {
    // stage A tile (M rows x 16 k): thread -> (mm = t/4, kg = (t%4)*4)
    int mm = t >> 2, kg = (t & 3) << 2;
    float4 a4 = *(const float4*)(A + (size_t)(m0 + mm) * K + k0 + kg);
    As[kg + 0][mm] = a4.x; As[kg + 1][mm] = a4.y;
    As[kg + 2][mm] = a4.z; As[kg + 3][mm] = a4.w;
    // stage B tile (16 k x 64 n): thread -> (kk = t/16, nn = (t%16)*4)
    int nn = tx << 2, kk = ty;
    int ncol = n0 + nn;
    if (ncol + 3 < N) {
      float4 b4 = *(const float4*)(Bm + (size_t)(k0 + kk) * N + ncol);
      Bs[kk][nn + 0] = b4.x; Bs[kk][nn + 1] = b4.y;
      Bs[kk][nn + 2] = b4.z; Bs[kk][nn + 3] = b4.w;
    } else {
      for (int j = 0; j < 4; ++j)
        Bs[kk][nn + j] = (ncol + j < N) ? Bm[(size_t)(k0 + kk) * N + ncol + j] : 0.0f;
    }
    __syncthreads();
#pragma unroll
    for (int k2 = 0; k2 < 16; ++k2) {
      float av[4], bv[4];
#pragma unroll
      for (int i = 0; i < 4; ++i) av[i] = As[k2][ty * 4 + i];
#pragma unroll
      for (int j = 0; j < 4; ++j) bv[j] = Bs[k2][tx * 4 + j];
#pragma unroll
      for (int i = 0; i < 4; ++i)
#pragma unroll
        for (int j = 0; j < 4; ++j)
          c[i][j] = fmaf(av[i], bv[j], c[i][j]);
    }
    __syncthreads();
  }
  for (int i = 0; i < 4; ++i) {
    int m = m0 + ty * 4 + i;
    for (int j = 0; j < 4; ++j) {
      int n = n0 + tx * 4 + j;
      if (m < M && n < N) {
        size_t idx = (size_t)m * N + n;
        float val = scale * c[i][j];
        if (ACC) C[idx] += val; else C[idx] = val;
      }
    }
  }
}

// ---------------- RoPE apply in-place on [B,S,H,DH] (pairs dh, dh+32) ----------------
__global__ void rope_apply_kernel(float* __restrict__ x, const float* __restrict__ cosb,
                                  const float* __restrict__ sinb) {
  int i = blockIdx.x * 256 + threadIdx.x;
  constexpr int total = B * S * H * 32;
  if (i >= total) return;
  int dh = i & 31;
  int rest = i >> 5;
  int hh = rest % H;
  int bs = rest / H;
  int s = bs % S;
  size_t base = (size_t)bs * D + hh * DH;
  float x1 = x[base + dh], x2 = x[base + dh + 32];
  float c = cosb[s * DH + dh], sn = sinb[s * DH + dh];
  x[base + dh]      = x1 * c - x2 * sn;
  x[base + dh + 32] = x2 * c + x1 * sn;
}

// ---------------- Attention: one wave per (b, h, q-row) ----------------
__global__ void attn_kernel(const float* __restrict__ q, const float* __restrict__ k,
                            const float* __restrict__ v, const int* __restrict__ mask,
                            float* __restrict__ o) {
  int idx = blockIdx.x;
  int qi = idx % S;
  int bh = idx / S;
  int hh = bh % H;
  int b  = bh / H;
  __shared__ float qs[DH];
  __shared__ float p[S];
  int t = threadIdx.x;  // 64 threads
  qs[t] = q[((size_t)(b * S + qi)) * D + hh * DH + t];
  __syncthreads();
  const float scale = 0.125f;  // 1/sqrt(64)
  for (int kk = t; kk < S; kk += 64) {
    float sc;
    if (kk <= qi && mask[b * S + kk] > 0) {
      const float* kp = k + ((size_t)(b * S + kk)) * D + hh * DH;
      float dot = 0.0f;
#pragma unroll 16
      for (int d = 0; d < DH; ++d) dot = fmaf(qs[d], kp[d], dot);
      sc = dot * scale;
    } else {
      sc = -1e9f;
    }
    p[kk] = sc;
  }
  __syncthreads();
  float mx = -1e30f;
  for (int kk = t; kk < S; kk += 64) mx = fmaxf(mx, p[kk]);
  for (int off = 32; off; off >>= 1) mx = fmaxf(mx, __shfl_xor(mx, off));
  float sum = 0.0f;
  for (int kk = t; kk < S; kk += 64) { float e = __expf(p[kk] - mx); p[kk] = e; sum += e; }
  for (int off = 32; off; off >>= 1) sum += __shfl_xor(sum, off);
  float rinv = 1.0f / sum;
  __syncthreads();
  // lane t owns head dim t; V reads coalesced across lanes
  float acc = 0.0f;
  const float* vp = v + ((size_t)(b * S)) * D + hh * DH + t;
  for (int kk = 0; kk <= qi; ++kk) acc = fmaf(p[kk], vp[(size_t)kk * D], acc);
  o[((size_t)(b * S + qi)) * D + hh * DH + t] = acc * rinv;
}

// ---------------- SwiGLU: g = silu(g) * u ----------------
__global__ void silu_mul_kernel(float* __restrict__ g, const float* __restrict__ u, int n) {
  int i = blockIdx.x * 256 + threadIdx.x;
  if (i < n) {
    float gv = g[i];
    float sg = 1.0f / (1.0f + __expf(-gv));
    g[i] = gv * sg * u[i];
  }
}

// ---------------- Value head: per-row dot ----------------
__global__ void value_kernel(const float* __restrict__ hf, const float* __restrict__ vw,
                             const float* __restrict__ vb, float* __restrict__ out) {
  int row = blockIdx.x, t = threadIdx.x;  // 256 threads
  float acc = 0.0f;
  for (int d = t; d < D; d += 256) acc = fmaf(hf[(size_t)row * D + d], vw[d], acc);
  __shared__ float red[256];
  red[t] = acc; __syncthreads();
  for (int s2 = 128; s2; s2 >>= 1) { if (t < s2) red[t] += red[t + s2]; __syncthreads(); }
  if (t == 0) out[row] = red[0] + vb[0];
}

static void gemm(const float* A, const float* Bm, float* C, int M, int N, int K,
                 float scale, bool acc, hipStream_t stream) {
  dim3 grid((N + 63) / 64, (M + 63) / 64);
  if (acc) gemm_kernel<true><<<grid, dim3(256), 0, stream>>>(A, Bm, C, M, N, K, scale);
  else     gemm_kernel<false><<<grid, dim3(256), 0, stream>>>(A, Bm, C, M, N, K, scale);
}

extern "C" void kernel_launch(void* const* d_in, const int* in_sizes, int n_in,
                              void* d_out, int out_size, void* d_ws, size_t ws_size,
                              hipStream_t stream) {
  const int*   ids     = (const int*)d_in[0];
  const int*   amask   = (const int*)d_in[1];
  const float* emb     = (const float*)d_in[2];
  const float* ln1     = (const float*)d_in[3];
  const float* ln2     = (const float*)d_in[4];
  const float* wq = (const float*)d_in[5],  *aq = (const float*)d_in[6],  *bq = (const float*)d_in[7];
  const float* wk = (const float*)d_in[8],  *ak = (const float*)d_in[9],  *bk = (const float*)d_in[10];
  const float* wv = (const float*)d_in[11], *av = (const float*)d_in[12], *bv = (const float*)d_in[13];
  const float* wo = (const float*)d_in[14], *ao = (const float*)d_in[15], *bo = (const float*)d_in[16];
  const float* wg = (const float*)d_in[17], *ag = (const float*)d_in[18], *bg = (const float*)d_in[19];
  const float* wu = (const float*)d_in[20], *au = (const float*)d_in[21], *bu = (const float*)d_in[22];
  const float* wd = (const float*)d_in[23], *ad = (const float*)d_in[24], *bd = (const float*)d_in[25];
  const float* final_ln  = (const float*)d_in[26];
  const float* lm_head_w = (const float*)d_in[27];
  const float* value_w   = (const float*)d_in[28];
  const float* value_b   = (const float*)d_in[29];

  float* out    = (float*)d_out;
  float* logits = out;                       // [B,S,V]
  float* values = out + (size_t)BS * V;      // [B,S]

  // workspace layout (floats): ~59 MB total
  float* W    = (float*)d_ws;
  float* cosb = W; W += S * DH;
  float* sinb = W; W += S * DH;
  float* h    = W; W += (size_t)BS * D;
  float* x    = W; W += (size_t)BS * D;
  float* qb   = W; W += (size_t)BS * D;
  float* kb   = W; W += (size_t)BS * D;
  float* vbuf = W; W += (size_t)BS * D;
  float* ob   = W; W += (size_t)BS * D;
  float* t2   = W; W += (size_t)BS * R;
  float* gb   = W; W += (size_t)BS * F;
  float* ub   = W; W += (size_t)BS * F;

  rope_cache_kernel<<<dim3(S), dim3(32), 0, stream>>>(cosb, sinb);
  embed_kernel<<<dim3(BS), dim3(256), 0, stream>>>(ids, emb, h);

  constexpr int ROPE_BLOCKS = (B * S * H * 32 + 255) / 256;

  for (int l = 0; l < L; ++l) {
    // ---- attention block ----
    rmsnorm_kernel<<<dim3(BS), dim3(256), 0, stream>>>(h, ln1 + (size_t)l * D, x);
    // q,k,v with LoRA: base + 2*(x@a)@b
    gemm(x, wq + (size_t)l * D * D, qb, BS, D, D, 1.0f, false, stream);
    gemm(x, aq + (size_t)l * D * R, t2, BS, R, D, 1.0f, false, stream);
    gemm(t2, bq + (size_t)l * R * D, qb, BS, D, R, LORA_SCALE, true, stream);
    gemm(x, wk + (size_t)l * D * D, kb, BS, D, D, 1.0f, false, stream);
    gemm(x, ak + (size_t)l * D * R, t2, BS, R, D, 1.0f, false, stream);
    gemm(t2, bk + (size_t)l * R * D, kb, BS, D, R, LORA_SCALE, true, stream);
    gemm(x, wv + (size_t)l * D * D, vbuf, BS, D, D, 1.0f, false, stream);
    gemm(x, av + (size_t)l * D * R, t2, BS, R, D, 1.0f, false, stream);
    gemm(t2, bv + (size_t)l * R * D, vbuf, BS, D, R, LORA_SCALE, true, stream);

    rope_apply_kernel<<<dim3(ROPE_BLOCKS), dim3(256), 0, stream>>>(qb, cosb, sinb);
    rope_apply_kernel<<<dim3(ROPE_BLOCKS), dim3(256), 0, stream>>>(kb, cosb, sinb);

    attn_kernel<<<dim3(B * H * S), dim3(64), 0, stream>>>(qb, kb, vbuf, amask, ob);

    // h += o@wo + 2*(o@ao)@bo
    gemm(ob, wo + (size_t)l * D * D, h, BS, D, D, 1.0f, true, stream);
    gemm(ob, ao + (size_t)l * D * R, t2, BS, R, D, 1.0f, false, stream);
    gemm(t2, bo + (size_t)l * R * D, h, BS, D, R, LORA_SCALE, true, stream);

    // ---- MLP block ----
    rmsnorm_kernel<<<dim3(BS), dim3(256), 0, stream>>>(h, ln2 + (size_t)l * D, x);
    gemm(x, wg + (size_t)l * D * F, gb, BS, F, D, 1.0f, false, stream);
    gemm(x, ag + (size_t)l * D * R, t2, BS, R, D, 1.0f, false, stream);
    gemm(t2, bg + (size_t)l * R * F, gb, BS, F, R, LORA_SCALE, true, stream);
    gemm(x, wu + (size_t)l * D * F, ub, BS, F, D, 1.0f, false, stream);
    gemm(x, au + (size_t)l * D * R, t2, BS, R, D, 1.0f, false, stream);
    gemm(t2, bu + (size_t)l * R * F, ub, BS, F, R, LORA_SCALE, true, stream);

    silu_mul_kernel<<<dim3((BS * F + 255) / 256), dim3(256), 0, stream>>>(gb, ub, BS * F);

    gemm(gb, wd + (size_t)l * F * D, h, BS, D, F, 1.0f, true, stream);
    gemm(gb, ad + (size_t)l * F * R, t2, BS, R, F, 1.0f, false, stream);
    gemm(t2, bd + (size_t)l * R * D, h, BS, D, R, LORA_SCALE, true, stream);
  }

  // ---- final norm + heads ----
  rmsnorm_kernel<<<dim3(BS), dim3(256), 0, stream>>>(h, final_ln, x);
  gemm(x, lm_head_w, logits, BS, V, D, 1.0f, false, stream);
  value_kernel<<<dim3(BS), dim3(256), 0, stream>>>(x, value_w, value_b, values);
}

// Round 2
// 1894.584 us; speedup vs baseline: 2.4505x; 2.4505x over previous
//
#include <hip/hip_runtime.h>
#include <math.h>

// LLaMA-style decoder forward: B=2 S=512 D=1024 H=16 F=4096 V=32000 L=2 R=16
constexpr int B = 2, S = 512, D = 1024, H = 16, F = 4096, V = 32000, L = 2, R = 16, DH = 64;
constexpr int BS = B * S;          // 1024 rows
constexpr float LORA_SCALE = 2.0f; // alpha/r = 32/16
constexpr float EPS = 1e-5f;

typedef __attribute__((ext_vector_type(8))) __bf16 bf16x8;
typedef __attribute__((ext_vector_type(4))) float f32x4;

__device__ __forceinline__ unsigned short f2bf(float f) {
  unsigned u = __builtin_bit_cast(unsigned, f);
  unsigned r = (u + 0x7FFFu + ((u >> 16) & 1u)) >> 16;  // RNE
  return (unsigned short)r;
}
__device__ __forceinline__ float bf2f(unsigned short us) {
  return __builtin_bit_cast(float, (unsigned)us << 16);
}
__device__ __forceinline__ void load_lds16(const void* g, void* l) {
  __builtin_amdgcn_global_load_lds((const __attribute__((address_space(1))) void*)g,
                                   (__attribute__((address_space(3))) void*)l, 16, 0, 0);
}

// ---------------- RoPE cache ----------------
__global__ void rope_cache_kernel(float* __restrict__ cosb, float* __restrict__ sinb) {
  int s = blockIdx.x, j = threadIdx.x;  // j in [0,32)
  float inv = __expf(-(float)j * (9.210340371976184f / 32.0f));
  float ang = (float)s * inv;
  float c = cosf(ang), sn = sinf(ang);
  cosb[s * DH + j] = c;  cosb[s * DH + j + 32] = c;
  sinb[s * DH + j] = sn; sinb[s * DH + j + 32] = sn;
}

// ---------------- Embedding gather ----------------
__global__ void embed_kernel(const int* __restrict__ ids, const float* __restrict__ emb,
                             float* __restrict__ h) {
  int row = blockIdx.x, t = threadIdx.x;
  int id = ids[row];
  ((float4*)(h + (size_t)row * D))[t] = ((const float4*)(emb + (size_t)id * D))[t];
}

// ---------------- RMSNorm -> bf16 output ----------------
__global__ void rmsnorm_bf16_kernel(const float* __restrict__ x, const float* __restrict__ w,
                                    unsigned short* __restrict__ y) {
  int row = blockIdx.x, t = threadIdx.x;  // 256 threads
  float4 xv = ((const float4*)(x + (size_t)row * D))[t];
  float ss = xv.x * xv.x + xv.y * xv.y + xv.z * xv.z + xv.w * xv.w;
  __shared__ float red[256];
  red[t] = ss; __syncthreads();
  for (int s2 = 128; s2; s2 >>= 1) { if (t < s2) red[t] += red[t + s2]; __syncthreads(); }
  float rinv = rsqrtf(red[0] * (1.0f / D) + EPS);
  float4 wv = ((const float4*)w)[t];
  ushort4 o;
  o.x = f2bf(xv.x * rinv * wv.x); o.y = f2bf(xv.y * rinv * wv.y);
  o.z = f2bf(xv.z * rinv * wv.z); o.w = f2bf(xv.w * rinv * wv.w);
  ((ushort4*)(y + (size_t)row * D))[t] = o;
}

// ---------------- f32 [K,N] -> bf16 [N,K] transpose-convert ----------------
__global__ void transpose_bf16_kernel(const float* __restrict__ src,
                                      unsigned short* __restrict__ dst, int K, int N) {
  __shared__ unsigned short tile[32][33];
  int n0 = blockIdx.x * 32, k0 = blockIdx.y * 32;
  int tx = threadIdx.x & 31, ty = threadIdx.x >> 5;  // 256 threads
  for (int i = ty; i < 32; i += 8)
    tile[i][tx] = f2bf(src[(size_t)(k0 + i) * N + n0 + tx]);
  __syncthreads();
  for (int i = ty; i < 32; i += 8)
    dst[(size_t)(n0 + i) * K + k0 + tx] = tile[tx][i];
}

// ---------------- bf16 MFMA GEMM (m97 structure): C = [C +] scale * A @ Bt^T ----------------
// A: [M,K] bf16 row-major.  Bt: [N,K] bf16 row-major (i.e. B transposed).  C: [M,N] f32.
// M,N multiples of 128; K multiple of 64.
template <bool ACC>
__global__ __launch_bounds__(256) void gemm_bf16_kernel(
    const unsigned short* __restrict__ A, const unsigned short* __restrict__ Bt,
    float* __restrict__ C, int M, int N, int K, float scale) {
  __shared__ __align__(16) unsigned short As[128 * 64];
  __shared__ __align__(16) unsigned short Bs[128 * 64];
  int t = threadIdx.x;
  int lane = t & 63, wave = t >> 6;
  int wr = wave >> 1, wc = wave & 1;              // 2x2 waves of 64x64
  int m0 = blockIdx.y * 128, n0 = blockIdx.x * 128;
  int fr = lane & 15;   // fragment row/col
  int fq = lane >> 4;   // k-quad 0..3
  f32x4 acc[4][4] = {};
  for (int k0 = 0; k0 < K; k0 += 64) {
#pragma unroll
    for (int c = 0; c < 4; ++c) {
      int i = c * 256 + t;            // 1024 16B-chunks per tile
      int row = i >> 3, cc = i & 7;   // row 0..127, 8 chunks of 8 bf16 per row
      load_lds16(A + (size_t)(m0 + row) * K + k0 + cc * 8, &As[i * 8]);
      load_lds16(Bt + (size_t)(n0 + row) * K + k0 + cc * 8, &Bs[i * 8]);
    }
    __syncthreads();
#pragma unroll
    for (int kk = 0; kk < 2; ++kk) {
      bf16x8 af[4], bfr[4];
#pragma unroll
      for (int mi = 0; mi < 4; ++mi)
        af[mi] = *(const bf16x8*)(As + (wr * 64 + mi * 16 + fr) * 64 + kk * 32 + fq * 8);
#pragma unroll
      for (int ni = 0; ni < 4; ++ni)
        bfr[ni] = *(const bf16x8*)(Bs + (wc * 64 + ni * 16 + fr) * 64 + kk * 32 + fq * 8);
#pragma unroll
      for (int mi = 0; mi < 4; ++mi)
#pragma unroll
        for (int ni = 0; ni < 4; ++ni)
          acc[mi][ni] = __builtin_amdgcn_mfma_f32_16x16x32_bf16(af[mi], bfr[ni], acc[mi][ni], 0, 0, 0);
    }
    __syncthreads();
  }
  // epilogue: C/D layout col=lane&15, row=(lane>>4)*4+j  [m89]
#pragma unroll
  for (int mi = 0; mi < 4; ++mi)
#pragma unroll
    for (int ni = 0; ni < 4; ++ni)
#pragma unroll
      for (int j = 0; j < 4; ++j) {
        int r = m0 + wr * 64 + mi * 16 + fq * 4 + j;
        int cl = n0 + wc * 64 + ni * 16 + fr;
        size_t idx = (size_t)r * N + cl;
        float v = scale * acc[mi][ni][j];
        C[idx] = ACC ? C[idx] + v : v;
      }
}

// ---------------- LoRA: t2[M,16] = x_bf16[M,K] @ a[K,16] ----------------
__global__ void lora_xa_kernel(const unsigned short* __restrict__ xb, const float* __restrict__ a,
                               float* __restrict__ t2, int K) {
  int row = blockIdx.x, t = threadIdx.x;  // 256 threads
  __shared__ float xs[4096];
  for (int k = t; k < K; k += 256) xs[k] = bf2f(xb[(size_t)row * K + k]);
  __syncthreads();
  int n = t & 15, g = t >> 4;  // 16 k-groups x 16 cols
  float s = 0.0f;
  for (int k = g; k < K; k += 16) s = fmaf(xs[k], a[k * 16 + n], s);
  __shared__ float red[256];
  red[t] = s; __syncthreads();
  for (int h2 = 128; h2 >= 16; h2 >>= 1) { if (t < h2) red[t] += red[t + h2]; __syncthreads(); }
  if (t < 16) t2[row * 16 + t] = red[t];
}

// ---------------- LoRA apply: y[M,N] += 2 * t2[M,16] @ b[16,N] ----------------
__global__ void lora_apply_kernel(const float* __restrict__ t2, const float* __restrict__ b,
                                  float* __restrict__ y, int N) {
  int idx = blockIdx.x * 256 + threadIdx.x;
  int row = idx / N, n = idx % N;
  const float* tp = t2 + row * 16;
  float s = 0.0f;
#pragma unroll
  for (int k = 0; k < 16; ++k) s = fmaf(tp[k], b[k * N + n], s);
  y[idx] += LORA_SCALE * s;
}

// ---------------- RoPE apply in-place on f32 [B,S,H,DH] ----------------
__global__ void rope_apply_kernel(float* __restrict__ x, const float* __restrict__ cosb,
                                  const float* __restrict__ sinb) {
  int i = blockIdx.x * 256 + threadIdx.x;
  constexpr int total = B * S * H * 32;
  if (i >= total) return;
  int dh = i & 31;
  int rest = i >> 5;
  int hh = rest % H;
  int bs = rest / H;
  int s = bs % S;
  size_t base = (size_t)bs * D + hh * DH;
  float x1 = x[base + dh], x2 = x[base + dh + 32];
  float c = cosb[s * DH + dh], sn = sinb[s * DH + dh];
  x[base + dh]      = x1 * c - x2 * sn;
  x[base + dh + 32] = x2 * c + x1 * sn;
}

// ---------------- Attention (f32 math, bf16 out): one wave per (b,h,q) ----------------
__global__ void attn_kernel(const float* __restrict__ q, const float* __restrict__ k,
                            const float* __restrict__ v, const int* __restrict__ mask,
                            unsigned short* __restrict__ o) {
  int idx = blockIdx.x;
  int qi = idx % S;
  int bh = idx / S;
  int hh = bh % H;
  int b  = bh / H;
  __shared__ float qs[DH];
  __shared__ float p[S];
  int t = threadIdx.x;  // 64 threads
  qs[t] = q[((size_t)(b * S + qi)) * D + hh * DH + t];
  __syncthreads();
  const float scale = 0.125f;
  for (int kk = t; kk < S; kk += 64) {
    float sc;
    if (kk <= qi && mask[b * S + kk] > 0) {
      const float* kp = k + ((size_t)(b * S + kk)) * D + hh * DH;
      float dot = 0.0f;
#pragma unroll 16
      for (int d = 0; d < DH; ++d) dot = fmaf(qs[d], kp[d], dot);
      sc = dot * scale;
    } else {
      sc = -1e9f;
    }
    p[kk] = sc;
  }
  __syncthreads();
  float mx = -1e30f;
  for (int kk = t; kk < S; kk += 64) mx = fmaxf(mx, p[kk]);
  for (int off = 32; off; off >>= 1) mx = fmaxf(mx, __shfl_xor(mx, off));
  float sum = 0.0f;
  for (int kk = t; kk < S; kk += 64) { float e = __expf(p[kk] - mx); p[kk] = e; sum += e; }
  for (int off = 32; off; off >>= 1) sum += __shfl_xor(sum, off);
  float rinv = 1.0f / sum;
  __syncthreads();
  float acc = 0.0f;
  const float* vp = v + ((size_t)(b * S)) * D + hh * DH + t;
  for (int kk = 0; kk <= qi; ++kk) acc = fmaf(p[kk], vp[(size_t)kk * D], acc);
  o[((size_t)(b * S + qi)) * D + hh * DH + t] = f2bf(acc * rinv);
}

// ---------------- SwiGLU: gbf = bf16(silu(g) * u) ----------------
__global__ void silu_mul_kernel(const float* __restrict__ g, const float* __restrict__ u,
                                unsigned short* __restrict__ gbf, int n) {
  int i = blockIdx.x * 256 + threadIdx.x;
  if (i < n) {
    float gv = g[i];
    float sg = 1.0f / (1.0f + __expf(-gv));
    gbf[i] = f2bf(gv * sg * u[i]);
  }
}

// ---------------- Value head ----------------
__global__ void value_kernel(const unsigned short* __restrict__ hf, const float* __restrict__ vw,
                             const float* __restrict__ vb, float* __restrict__ out) {
  int row = blockIdx.x, t = threadIdx.x;
  float acc = 0.0f;
  for (int d = t; d < D; d += 256) acc = fmaf(bf2f(hf[(size_t)row * D + d]), vw[d], acc);
  __shared__ float red[256];
  red[t] = acc; __syncthreads();
  for (int s2 = 128; s2; s2 >>= 1) { if (t < s2) red[t] += red[t + s2]; __syncthreads(); }
  if (t == 0) out[row] = red[0] + vb[0];
}

static void gemmb(const unsigned short* A, const unsigned short* Bt, float* C,
                  int M, int N, int K, float scale, bool acc, hipStream_t stream) {
  dim3 grid(N / 128, M / 128);
  if (acc) gemm_bf16_kernel<true><<<grid, 256, 0, stream>>>(A, Bt, C, M, N, K, scale);
  else     gemm_bf16_kernel<false><<<grid, 256, 0, stream>>>(A, Bt, C, M, N, K, scale);
}

extern "C" void kernel_launch(void* const* d_in, const int* in_sizes, int n_in,
                              void* d_out, int out_size, void* d_ws, size_t ws_size,
                              hipStream_t stream) {
  const int*   ids     = (const int*)d_in[0];
  const int*   amask   = (const int*)d_in[1];
  const float* emb     = (const float*)d_in[2];
  const float* ln1     = (const float*)d_in[3];
  const float* ln2     = (const float*)d_in[4];
  const float* wq = (const float*)d_in[5],  *aq = (const float*)d_in[6],  *bq = (const float*)d_in[7];
  const float* wk = (const float*)d_in[8],  *ak = (const float*)d_in[9],  *bk = (const float*)d_in[10];
  const float* wv = (const float*)d_in[11], *av = (const float*)d_in[12], *bv = (const float*)d_in[13];
  const float* wo = (const float*)d_in[14], *ao = (const float*)d_in[15], *bo = (const float*)d_in[16];
  const float* wg = (const float*)d_in[17], *ag = (const float*)d_in[18], *bg = (const float*)d_in[19];
  const float* wu = (const float*)d_in[20], *au = (const float*)d_in[21], *bu = (const float*)d_in[22];
  const float* wd = (const float*)d_in[23], *ad = (const float*)d_in[24], *bd = (const float*)d_in[25];
  const float* final_ln  = (const float*)d_in[26];
  const float* lm_head_w = (const float*)d_in[27];
  const float* value_w   = (const float*)d_in[28];
  const float* value_b   = (const float*)d_in[29];

  float* out    = (float*)d_out;
  float* logits = out;
  float* values = out + (size_t)BS * V;

  // ---- workspace layout ----
  float* Wf = (float*)d_ws;
  float* cosb = Wf; Wf += S * DH;
  float* sinb = Wf; Wf += S * DH;
  float* h    = Wf; Wf += (size_t)BS * D;
  float* qb   = Wf; Wf += (size_t)BS * D;
  float* kb   = Wf; Wf += (size_t)BS * D;
  float* vbuf = Wf; Wf += (size_t)BS * D;
  float* gb   = Wf; Wf += (size_t)BS * F;
  float* ub   = Wf; Wf += (size_t)BS * F;
  float* t2   = Wf; Wf += (size_t)BS * R;
  unsigned short* Wb = (unsigned short*)Wf;
  unsigned short* x_bf = Wb; Wb += (size_t)BS * D;
  unsigned short* obf  = Wb; Wb += (size_t)BS * D;
  unsigned short* gbf  = Wb; Wb += (size_t)BS * F;
  unsigned short* wqT = Wb; Wb += (size_t)L * D * D;
  unsigned short* wkT = Wb; Wb += (size_t)L * D * D;
  unsigned short* wvT = Wb; Wb += (size_t)L * D * D;
  unsigned short* woT = Wb; Wb += (size_t)L * D * D;
  unsigned short* wgT = Wb; Wb += (size_t)L * D * F;
  unsigned short* wuT = Wb; Wb += (size_t)L * D * F;
  unsigned short* wdT = Wb; Wb += (size_t)L * F * D;
  unsigned short* lmT = Wb; Wb += (size_t)D * V;

  // ---- weight convert+transpose (every call; no cached state allowed) ----
  auto T = [&](const float* src, unsigned short* dst, int K_, int N_) {
    transpose_bf16_kernel<<<dim3(N_ / 32, K_ / 32), 256, 0, stream>>>(src, dst, K_, N_);
  };
  for (int l = 0; l < L; ++l) {
    T(wq + (size_t)l * D * D, wqT + (size_t)l * D * D, D, D);
    T(wk + (size_t)l * D * D, wkT + (size_t)l * D * D, D, D);
    T(wv + (size_t)l * D * D, wvT + (size_t)l * D * D, D, D);
    T(wo + (size_t)l * D * D, woT + (size_t)l * D * D, D, D);
    T(wg + (size_t)l * D * F, wgT + (size_t)l * D * F, D, F);
    T(wu + (size_t)l * D * F, wuT + (size_t)l * D * F, D, F);
    T(wd + (size_t)l * F * D, wdT + (size_t)l * F * D, F, D);
  }
  T(lm_head_w, lmT, D, V);

  rope_cache_kernel<<<dim3(S), dim3(32), 0, stream>>>(cosb, sinb);
  embed_kernel<<<dim3(BS), dim3(256), 0, stream>>>(ids, emb, h);

  constexpr int ROPE_BLOCKS = (B * S * H * 32 + 255) / 256;

  for (int l = 0; l < L; ++l) {
    size_t oDD = (size_t)l * D * D, oDR = (size_t)l * D * R, oRD = (size_t)l * R * D;
    size_t oDF = (size_t)l * D * F, oRF = (size_t)l * R * F, oFD = (size_t)l * F * D;
    size_t oFR = (size_t)l * F * R;

    // ---- attention block ----
    rmsnorm_bf16_kernel<<<dim3(BS), 256, 0, stream>>>(h, ln1 + (size_t)l * D, x_bf);
    gemmb(x_bf, wqT + oDD, qb, BS, D, D, 1.0f, false, stream);
    lora_xa_kernel<<<dim3(BS), 256, 0, stream>>>(x_bf, aq + oDR, t2, D);
    lora_apply_kernel<<<dim3(BS * D / 256), 256, 0, stream>>>(t2, bq + oRD, qb, D);
    gemmb(x_bf, wkT + oDD, kb, BS, D, D, 1.0f, false, stream);
    lora_xa_kernel<<<dim3(BS), 256, 0, stream>>>(x_bf, ak + oDR, t2, D);
    lora_apply_kernel<<<dim3(BS * D / 256), 256, 0, stream>>>(t2, bk + oRD, kb, D);
    gemmb(x_bf, wvT + oDD, vbuf, BS, D, D, 1.0f, false, stream);
    lora_xa_kernel<<<dim3(BS), 256, 0, stream>>>(x_bf, av + oDR, t2, D);
    lora_apply_kernel<<<dim3(BS * D / 256), 256, 0, stream>>>(t2, bv + oRD, vbuf, D);

    rope_apply_kernel<<<dim3(ROPE_BLOCKS), 256, 0, stream>>>(qb, cosb, sinb);
    rope_apply_kernel<<<dim3(ROPE_BLOCKS), 256, 0, stream>>>(kb, cosb, sinb);

    attn_kernel<<<dim3(B * H * S), dim3(64), 0, stream>>>(qb, kb, vbuf, amask, obf);

    gemmb(obf, woT + oDD, h, BS, D, D, 1.0f, true, stream);
    lora_xa_kernel<<<dim3(BS), 256, 0, stream>>>(obf, ao + oDR, t2, D);
    lora_apply_kernel<<<dim3(BS * D / 256), 256, 0, stream>>>(t2, bo + oRD, h, D);

    // ---- MLP block ----
    rmsnorm_bf16_kernel<<<dim3(BS), 256, 0, stream>>>(h, ln2 + (size_t)l * D, x_bf);
    gemmb(x_bf, wgT + oDF, gb, BS, F, D, 1.0f, false, stream);
    lora_xa_kernel<<<dim3(BS), 256, 0, stream>>>(x_bf, ag + oDR, t2, D);
    lora_apply_kernel<<<dim3(BS * F / 256), 256, 0, stream>>>(t2, bg + oRF, gb, F);
    gemmb(x_bf, wuT + oDF, ub, BS, F, D, 1.0f, false, stream);
    lora_xa_kernel<<<dim3(BS), 256, 0, stream>>>(x_bf, au + oDR, t2, D);
    lora_apply_kernel<<<dim3(BS * F / 256), 256, 0, stream>>>(t2, bu + oRF, ub, F);

    silu_mul_kernel<<<dim3(BS * F / 256), 256, 0, stream>>>(gb, ub, gbf, BS * F);

    gemmb(gbf, wdT + oFD, h, BS, D, F, 1.0f, true, stream);
    lora_xa_kernel<<<dim3(BS), 256, 0, stream>>>(gbf, ad + oFR, t2, F);
    lora_apply_kernel<<<dim3(BS * D / 256), 256, 0, stream>>>(t2, bd + oRD, h, D);
  }

  // ---- final norm + heads ----
  rmsnorm_bf16_kernel<<<dim3(BS), 256, 0, stream>>>(h, final_ln, x_bf);
  gemmb(x_bf, lmT, logits, BS, V, D, 1.0f, false, stream);
  value_kernel<<<dim3(BS), 256, 0, stream>>>(x_bf, value_w, value_b, values);
}

// Round 3
// 1302.870 us; speedup vs baseline: 3.5634x; 1.4542x over previous
//
#include <hip/hip_runtime.h>
#include <math.h>

// LLaMA-style decoder forward: B=2 S=512 D=1024 H=16 F=4096 V=32000 L=2 R=16
constexpr int B = 2, S = 512, D = 1024, H = 16, F = 4096, V = 32000, L = 2, R = 16, DH = 64;
constexpr int BS = B * S;          // 1024 rows
constexpr float LORA_SCALE = 2.0f; // alpha/r
constexpr float EPS = 1e-5f;
constexpr int RS_QKV = 3 * D;      // fused qkv row stride
constexpr int RS_GU  = 2 * F;      // fused g|u row stride

typedef __attribute__((ext_vector_type(8))) __bf16 bf16x8;
typedef __attribute__((ext_vector_type(4))) float f32x4;

__device__ __forceinline__ unsigned short f2bf(float f) {
  unsigned u = __builtin_bit_cast(unsigned, f);
  unsigned r = (u + 0x7FFFu + ((u >> 16) & 1u)) >> 16;  // RNE
  return (unsigned short)r;
}
__device__ __forceinline__ float bf2f(unsigned short us) {
  return __builtin_bit_cast(float, (unsigned)us << 16);
}
__device__ __forceinline__ void load_lds16(const void* g, void* l) {
  __builtin_amdgcn_global_load_lds((const __attribute__((address_space(1))) void*)g,
                                   (__attribute__((address_space(3))) void*)l, 16, 0, 0);
}

struct Ptr3 { const float* p[3]; };

// ---------------- RoPE cache ----------------
__global__ void rope_cache_kernel(float* __restrict__ cosb, float* __restrict__ sinb) {
  int s = blockIdx.x, j = threadIdx.x;  // j in [0,32)
  float inv = __expf(-(float)j * (9.210340371976184f / 32.0f));
  float ang = (float)s * inv;
  float c = cosf(ang), sn = sinf(ang);
  cosb[s * DH + j] = c;  cosb[s * DH + j + 32] = c;
  sinb[s * DH + j] = sn; sinb[s * DH + j + 32] = sn;
}

// ---------------- Embedding gather ----------------
__global__ void embed_kernel(const int* __restrict__ ids, const float* __restrict__ emb,
                             float* __restrict__ h) {
  int row = blockIdx.x, t = threadIdx.x;
  int id = ids[row];
  ((float4*)(h + (size_t)row * D))[t] = ((const float4*)(emb + (size_t)id * D))[t];
}

// ---------------- RMSNorm -> bf16 ----------------
__global__ void rmsnorm_bf16_kernel(const float* __restrict__ x, const float* __restrict__ w,
                                    unsigned short* __restrict__ y) {
  int row = blockIdx.x, t = threadIdx.x;
  float4 xv = ((const float4*)(x + (size_t)row * D))[t];
  float ss = xv.x * xv.x + xv.y * xv.y + xv.z * xv.z + xv.w * xv.w;
  __shared__ float red[256];
  red[t] = ss; __syncthreads();
  for (int s2 = 128; s2; s2 >>= 1) { if (t < s2) red[t] += red[t + s2]; __syncthreads(); }
  float rinv = rsqrtf(red[0] * (1.0f / D) + EPS);
  float4 wv = ((const float4*)w)[t];
  ushort4 o;
  o.x = f2bf(xv.x * rinv * wv.x); o.y = f2bf(xv.y * rinv * wv.y);
  o.z = f2bf(xv.z * rinv * wv.z); o.w = f2bf(xv.w * rinv * wv.w);
  ((ushort4*)(y + (size_t)row * D))[t] = o;
}

// ---------------- f32 [K,N] -> bf16 [N,K] transpose (64x64, vectorized) ----------------
__global__ __launch_bounds__(256) void transpose_bf16_kernel(const float* __restrict__ src,
                                      unsigned short* __restrict__ dst, int K, int N) {
  __shared__ unsigned short tile[64 * 72];
  int n0 = blockIdx.x * 64, k0 = blockIdx.y * 64;
  int t = threadIdx.x;
  int rr = t >> 4, c4 = (t & 15) << 2;
#pragma unroll
  for (int i = 0; i < 4; ++i) {
    int row = i * 16 + rr;
    float4 v = *(const float4*)(src + (size_t)(k0 + row) * N + n0 + c4);
    tile[(c4 + 0) * 72 + row] = f2bf(v.x);
    tile[(c4 + 1) * 72 + row] = f2bf(v.y);
    tile[(c4 + 2) * 72 + row] = f2bf(v.z);
    tile[(c4 + 3) * 72 + row] = f2bf(v.w);
  }
  __syncthreads();
#pragma unroll
  for (int i = 0; i < 4; ++i) {
    int row = i * 16 + rr;
    *(ushort4*)(dst + (size_t)(n0 + row) * K + k0 + c4) = *(const ushort4*)(tile + row * 72 + c4);
  }
}

// ---------------- bf16 MFMA GEMM: C = [C +] scale * A @ Bt^T ----------------
// A:[M,K] bf16, Bt:[N,K] bf16, C:[M,N] f32.  M%128==0, N%BN==0, K%64==0.
template <int BN, bool ACC>
__global__ __launch_bounds__(256) void gemm_bf16_kernel(
    const unsigned short* __restrict__ A, const unsigned short* __restrict__ Bt,
    float* __restrict__ C, int M, int N, int K, float scale) {
  constexpr int WM = (BN == 128) ? 2 : 4;   // wave grid rows
  constexpr int RW = 128 / WM;              // rows per wave
  constexpr int MI = RW / 16;
  constexpr int BCH = BN / 32;              // B staging iters (4 or 2)
  __shared__ __align__(16) unsigned short As[128 * 64];
  __shared__ __align__(16) unsigned short Bs[BN * 64];
  int t = threadIdx.x;
  int lane = t & 63, wave = t >> 6;
  int wr = (BN == 128) ? (wave >> 1) : wave;
  int wc = (BN == 128) ? (wave & 1) : 0;
  int m0 = blockIdx.y * 128, n0 = blockIdx.x * BN;
  int fr = lane & 15, fq = lane >> 4;
  f32x4 acc[MI][4] = {};
  for (int k0 = 0; k0 < K; k0 += 64) {
#pragma unroll
    for (int c = 0; c < 4; ++c) {
      int i = c * 256 + t;
      int row = i >> 3, cc = i & 7;
      load_lds16(A + (size_t)(m0 + row) * K + k0 + cc * 8, &As[i * 8]);
    }
#pragma unroll
    for (int c = 0; c < BCH; ++c) {
      int i = c * 256 + t;
      int row = i >> 3, cc = i & 7;
      load_lds16(Bt + (size_t)(n0 + row) * K + k0 + cc * 8, &Bs[i * 8]);
    }
    __syncthreads();
#pragma unroll
    for (int kk = 0; kk < 2; ++kk) {
      bf16x8 af[MI], bfr[4];
#pragma unroll
      for (int mi = 0; mi < MI; ++mi)
        af[mi] = *(const bf16x8*)(As + (wr * RW + mi * 16 + fr) * 64 + kk * 32 + fq * 8);
#pragma unroll
      for (int ni = 0; ni < 4; ++ni)
        bfr[ni] = *(const bf16x8*)(Bs + (wc * 64 + ni * 16 + fr) * 64 + kk * 32 + fq * 8);
#pragma unroll
      for (int mi = 0; mi < MI; ++mi)
#pragma unroll
        for (int ni = 0; ni < 4; ++ni)
          acc[mi][ni] = __builtin_amdgcn_mfma_f32_16x16x32_bf16(af[mi], bfr[ni], acc[mi][ni], 0, 0, 0);
    }
    __syncthreads();
  }
#pragma unroll
  for (int mi = 0; mi < MI; ++mi)
#pragma unroll
    for (int ni = 0; ni < 4; ++ni)
#pragma unroll
      for (int j = 0; j < 4; ++j) {
        int r = m0 + wr * RW + mi * 16 + fq * 4 + j;
        int cl = n0 + wc * 64 + ni * 16 + fr;
        size_t idx = (size_t)r * N + cl;
        float v = scale * acc[mi][ni][j];
        C[idx] = ACC ? C[idx] + v : v;
      }
}

// ---------------- LoRA: t2[M, NA*16] = x_bf16[M,K] @ [a0|a1|a2] ----------------
template <int NA>
__global__ void lora_xa_kernel(const unsigned short* __restrict__ xb, Ptr3 ap,
                               float* __restrict__ t2, int K) {
  int row = blockIdx.x, t = threadIdx.x;  // 256 threads
  __shared__ float xs[4096];
  __shared__ float red[256];
  for (int k = t; k < K; k += 256) xs[k] = bf2f(xb[(size_t)row * K + k]);
  __syncthreads();
  int n = t & 15, g = t >> 4;
#pragma unroll
  for (int ad = 0; ad < NA; ++ad) {
    const float* a = ap.p[ad];
    float s = 0.0f;
    for (int k = g; k < K; k += 16) s = fmaf(xs[k], a[k * 16 + n], s);
    red[t] = s; __syncthreads();
    for (int h2 = 128; h2 >= 16; h2 >>= 1) { if (t < h2) red[t] += red[t + h2]; __syncthreads(); }
    if (t < 16) t2[row * (NA * 16) + ad * 16 + t] = red[t];
    __syncthreads();
  }
}

// ---------------- LoRA apply: y[M, NA*W] += 2 * t2 @ b_sel ; grid (NA*W/256, M) ----------------
template <int NA>
__global__ void lora_apply_kernel(const float* __restrict__ t2, Ptr3 bp,
                                  float* __restrict__ y, int W, int LW) {
  int n = blockIdx.x * 256 + threadIdx.x;
  int row = blockIdx.y;
  int sel = n >> LW, nn = n & (W - 1);
  const float* tp = t2 + row * (NA * 16) + sel * 16;
  const float* b = bp.p[sel];
  float s = 0.0f;
#pragma unroll
  for (int k = 0; k < 16; ++k) s = fmaf(tp[k], b[k * W + nn], s);
  y[(size_t)row * (NA * W) + n] += LORA_SCALE * s;
}

// ---------------- RoPE apply in-place, strided rows ----------------
__global__ void rope_apply_kernel(float* __restrict__ x, const float* __restrict__ cosb,
                                  const float* __restrict__ sinb, int rstride) {
  int i = blockIdx.x * 256 + threadIdx.x;
  constexpr int total = B * S * H * 32;
  if (i >= total) return;
  int dh = i & 31;
  int rest = i >> 5;
  int hh = rest % H;
  int bs = rest / H;
  int s = bs % S;
  size_t base = (size_t)bs * rstride + hh * DH;
  float x1 = x[base + dh], x2 = x[base + dh + 32];
  float c = cosb[s * DH + dh], sn = sinb[s * DH + dh];
  x[base + dh]      = x1 * c - x2 * sn;
  x[base + dh + 32] = x2 * c + x1 * sn;
}

// ---------------- Flash attention, bf16 MFMA ----------------
// Block: 256 thr = 4 waves; one block per (b, h, q-tile of 64). Wave w: q rows [w*16, w*16+16).
__global__ __launch_bounds__(256) void attn_mfma_kernel(
    const float* __restrict__ qkv, const int* __restrict__ amask,
    unsigned short* __restrict__ o) {
  __shared__ unsigned short Qs[64 * 72];
  __shared__ unsigned short Ks[64 * 72];
  __shared__ unsigned short Vt[64 * 72];   // [dh][key]
  __shared__ unsigned short Ps[4][16 * 72];
  __shared__ float msk[64];
  int bid = blockIdx.x;
  int qt = bid & 7, hh = (bid >> 3) & (H - 1), b = bid >> 7;
  int t = threadIdx.x;
  int lane = t & 63, w = t >> 6;
  int fr = lane & 15, fq = lane >> 4;
  int rr = t >> 4, c4 = (t & 15) << 2;
  size_t rowbase = (size_t)b * S;
  int q0 = qt * 64;
  const float scale = 0.125f;  // 1/sqrt(64)
  // stage Q tile (rope already applied, f32 -> bf16)
#pragma unroll
  for (int i = 0; i < 4; ++i) {
    int row = i * 16 + rr;
    float4 v = *(const float4*)(qkv + (rowbase + q0 + row) * RS_QKV + hh * DH + c4);
    Qs[row * 72 + c4 + 0] = f2bf(v.x); Qs[row * 72 + c4 + 1] = f2bf(v.y);
    Qs[row * 72 + c4 + 2] = f2bf(v.z); Qs[row * 72 + c4 + 3] = f2bf(v.w);
  }
  f32x4 oacc[4] = {};
  float m_old[4] = {-1e30f, -1e30f, -1e30f, -1e30f};
  float l[4] = {};
  int qbase = q0 + w * 16;
  for (int kt = 0; kt <= qt; ++kt) {
    int kk0 = kt * 64;
    // stage K [key][dh] and V^T [dh][key]
#pragma unroll
    for (int i = 0; i < 4; ++i) {
      int row = i * 16 + rr;
      float4 kv = *(const float4*)(qkv + (rowbase + kk0 + row) * RS_QKV + D + hh * DH + c4);
      Ks[row * 72 + c4 + 0] = f2bf(kv.x); Ks[row * 72 + c4 + 1] = f2bf(kv.y);
      Ks[row * 72 + c4 + 2] = f2bf(kv.z); Ks[row * 72 + c4 + 3] = f2bf(kv.w);
      float4 vv = *(const float4*)(qkv + (rowbase + kk0 + row) * RS_QKV + 2 * D + hh * DH + c4);
      Vt[(c4 + 0) * 72 + row] = f2bf(vv.x); Vt[(c4 + 1) * 72 + row] = f2bf(vv.y);
      Vt[(c4 + 2) * 72 + row] = f2bf(vv.z); Vt[(c4 + 3) * 72 + row] = f2bf(vv.w);
    }
    if (t < 64) msk[t] = (amask[b * S + kk0 + t] > 0) ? 0.0f : -1e9f;
    __syncthreads();
    // S = Q @ K^T for this wave's 16 q-rows x 64 keys
    bf16x8 aq[2];
    aq[0] = *(const bf16x8*)(Qs + (w * 16 + fr) * 72 + fq * 8);
    aq[1] = *(const bf16x8*)(Qs + (w * 16 + fr) * 72 + 32 + fq * 8);
    f32x4 sacc[4];
#pragma unroll
    for (int ct = 0; ct < 4; ++ct) {
      bf16x8 bk0 = *(const bf16x8*)(Ks + (ct * 16 + fr) * 72 + fq * 8);
      bf16x8 bk1 = *(const bf16x8*)(Ks + (ct * 16 + fr) * 72 + 32 + fq * 8);
      f32x4 z = {};
      z = __builtin_amdgcn_mfma_f32_16x16x32_bf16(aq[0], bk0, z, 0, 0, 0);
      sacc[ct] = __builtin_amdgcn_mfma_f32_16x16x32_bf16(aq[1], bk1, z, 0, 0, 0);
    }
    // masked scores + online softmax (rows j=0..3 of group fq)
    float sv[4][4];
#pragma unroll
    for (int ct = 0; ct < 4; ++ct) {
      int kg = kk0 + ct * 16 + fr;
      float mk = msk[ct * 16 + fr];
#pragma unroll
      for (int j = 0; j < 4; ++j) {
        int qg = qbase + fq * 4 + j;
        float s = sacc[ct][j] * scale + mk;
        sv[ct][j] = (kg > qg) ? -1e9f : s;
      }
    }
    float mnew[4], f[4], rsum[4];
#pragma unroll
    for (int j = 0; j < 4; ++j) {
      float mt = fmaxf(fmaxf(sv[0][j], sv[1][j]), fmaxf(sv[2][j], sv[3][j]));
      for (int off = 1; off < 16; off <<= 1) mt = fmaxf(mt, __shfl_xor(mt, off));
      mnew[j] = fmaxf(m_old[j], mt);
      f[j] = __expf(m_old[j] - mnew[j]);
      float rs = 0.0f;
#pragma unroll
      for (int ct = 0; ct < 4; ++ct) {
        float e = __expf(sv[ct][j] - mnew[j]);
        sv[ct][j] = e;
        rs += e;
      }
      for (int off = 1; off < 16; off <<= 1) rs += __shfl_xor(rs, off);
      rsum[j] = rs;
      l[j] = l[j] * f[j] + rsum[j];
      m_old[j] = mnew[j];
#pragma unroll
      for (int dt = 0; dt < 4; ++dt) oacc[dt][j] *= f[j];
    }
    // write P (bf16) to this wave's LDS strip
#pragma unroll
    for (int ct = 0; ct < 4; ++ct)
#pragma unroll
      for (int j = 0; j < 4; ++j)
        Ps[w][(fq * 4 + j) * 72 + ct * 16 + fr] = f2bf(sv[ct][j]);
    __syncthreads();
    // O += P @ V  (A = P[16 q][64 k], B = V[64 k][64 dh] via Vt)
    bf16x8 pa[2];
    pa[0] = *(const bf16x8*)(&Ps[w][fr * 72 + fq * 8]);
    pa[1] = *(const bf16x8*)(&Ps[w][fr * 72 + 32 + fq * 8]);
#pragma unroll
    for (int dt = 0; dt < 4; ++dt) {
      bf16x8 vb0 = *(const bf16x8*)(Vt + (dt * 16 + fr) * 72 + fq * 8);
      bf16x8 vb1 = *(const bf16x8*)(Vt + (dt * 16 + fr) * 72 + 32 + fq * 8);
      oacc[dt] = __builtin_amdgcn_mfma_f32_16x16x32_bf16(pa[0], vb0, oacc[dt], 0, 0, 0);
      oacc[dt] = __builtin_amdgcn_mfma_f32_16x16x32_bf16(pa[1], vb1, oacc[dt], 0, 0, 0);
    }
    __syncthreads();
  }
  // write O (bf16) to [BS][D]
#pragma unroll
  for (int j = 0; j < 4; ++j) {
    float rinv = 1.0f / l[j];
    int qrow = qbase + fq * 4 + j;
#pragma unroll
    for (int dt = 0; dt < 4; ++dt)
      o[(rowbase + qrow) * D + hh * DH + dt * 16 + fr] = f2bf(oacc[dt][j] * rinv);
  }
}

// ---------------- SwiGLU on fused [BS][2F]: gbf = bf16(silu(g)*u) ----------------
__global__ void silu_mul_kernel(const float* __restrict__ gu, unsigned short* __restrict__ gbf) {
  int i = blockIdx.x * 256 + threadIdx.x;  // over BS*F
  int row = i >> 12, j = i & (F - 1);
  float gv = gu[(size_t)row * RS_GU + j];
  float uv = gu[(size_t)row * RS_GU + F + j];
  float sg = 1.0f / (1.0f + __expf(-gv));
  gbf[i] = f2bf(gv * sg * uv);
}

// ---------------- Value head ----------------
__global__ void value_kernel(const unsigned short* __restrict__ hf, const float* __restrict__ vw,
                             const float* __restrict__ vb, float* __restrict__ out) {
  int row = blockIdx.x, t = threadIdx.x;
  float acc = 0.0f;
  for (int d = t; d < D; d += 256) acc = fmaf(bf2f(hf[(size_t)row * D + d]), vw[d], acc);
  __shared__ float red[256];
  red[t] = acc; __syncthreads();
  for (int s2 = 128; s2; s2 >>= 1) { if (t < s2) red[t] += red[t + s2]; __syncthreads(); }
  if (t == 0) out[row] = red[0] + vb[0];
}

static void gemmb(const unsigned short* A, const unsigned short* Bt, float* C,
                  int M, int N, int K, float scale, bool acc, hipStream_t stream) {
  if (N <= 1024) {
    dim3 grid(N / 64, M / 128);
    if (acc) gemm_bf16_kernel<64, true><<<grid, 256, 0, stream>>>(A, Bt, C, M, N, K, scale);
    else     gemm_bf16_kernel<64, false><<<grid, 256, 0, stream>>>(A, Bt, C, M, N, K, scale);
  } else {
    dim3 grid(N / 128, M / 128);
    if (acc) gemm_bf16_kernel<128, true><<<grid, 256, 0, stream>>>(A, Bt, C, M, N, K, scale);
    else     gemm_bf16_kernel<128, false><<<grid, 256, 0, stream>>>(A, Bt, C, M, N, K, scale);
  }
}

extern "C" void kernel_launch(void* const* d_in, const int* in_sizes, int n_in,
                              void* d_out, int out_size, void* d_ws, size_t ws_size,
                              hipStream_t stream) {
  const int*   ids     = (const int*)d_in[0];
  const int*   amask   = (const int*)d_in[1];
  const float* emb     = (const float*)d_in[2];
  const float* ln1     = (const float*)d_in[3];
  const float* ln2     = (const float*)d_in[4];
  const float* wq = (const float*)d_in[5],  *aq = (const float*)d_in[6],  *bq = (const float*)d_in[7];
  const float* wk = (const float*)d_in[8],  *ak = (const float*)d_in[9],  *bk = (const float*)d_in[10];
  const float* wv = (const float*)d_in[11], *av = (const float*)d_in[12], *bv = (const float*)d_in[13];
  const float* wo = (const float*)d_in[14], *ao = (const float*)d_in[15], *bo = (const float*)d_in[16];
  const float* wg = (const float*)d_in[17], *ag = (const float*)d_in[18], *bg = (const float*)d_in[19];
  const float* wu = (const float*)d_in[20], *au = (const float*)d_in[21], *bu = (const float*)d_in[22];
  const float* wd = (const float*)d_in[23], *ad = (const float*)d_in[24], *bd = (const float*)d_in[25];
  const float* final_ln  = (const float*)d_in[26];
  const float* lm_head_w = (const float*)d_in[27];
  const float* value_w   = (const float*)d_in[28];
  const float* value_b   = (const float*)d_in[29];

  float* out    = (float*)d_out;
  float* logits = out;
  float* values = out + (size_t)BS * V;

  // ---- workspace ----
  float* Wf = (float*)d_ws;
  float* cosb = Wf; Wf += S * DH;
  float* sinb = Wf; Wf += S * DH;
  float* h    = Wf; Wf += (size_t)BS * D;
  float* qkv  = Wf; Wf += (size_t)BS * RS_QKV;
  float* gu   = Wf; Wf += (size_t)BS * RS_GU;
  float* t2   = Wf; Wf += (size_t)BS * 48;
  unsigned short* Wb = (unsigned short*)Wf;
  unsigned short* x_bf  = Wb; Wb += (size_t)BS * D;
  unsigned short* wqkvT = Wb; Wb += (size_t)L * 3 * D * D;
  unsigned short* woT   = Wb; Wb += (size_t)L * D * D;
  unsigned short* wguT  = Wb; Wb += (size_t)L * 2 * D * F;
  unsigned short* wdT   = Wb; Wb += (size_t)L * F * D;
  unsigned short* lmT   = Wb; Wb += (size_t)D * V;
  // aliases into dead regions (obf dead before gu written; gbf dead before next qkv)
  unsigned short* obf = (unsigned short*)gu;   // [BS][D] bf16 = 2MB inside 33MB gu
  unsigned short* gbf = (unsigned short*)qkv;  // [BS][F] bf16 = 8.4MB inside 12.6MB qkv

  auto T = [&](const float* src, unsigned short* dst, int K_, int N_) {
    transpose_bf16_kernel<<<dim3(N_ / 64, K_ / 64), 256, 0, stream>>>(src, dst, K_, N_);
  };
  for (int l = 0; l < L; ++l) {
    size_t DD = (size_t)D * D, DF = (size_t)D * F;
    T(wq + l * DD, wqkvT + (size_t)l * 3 * DD, D, D);
    T(wk + l * DD, wqkvT + (size_t)l * 3 * DD + DD, D, D);
    T(wv + l * DD, wqkvT + (size_t)l * 3 * DD + 2 * DD, D, D);
    T(wo + l * DD, woT + l * DD, D, D);
    T(wg + l * DF, wguT + (size_t)l * 2 * DF, D, F);
    T(wu + l * DF, wguT + (size_t)l * 2 * DF + DF, D, F);
    T(wd + l * DF, wdT + l * DF, F, D);
  }
  T(lm_head_w, lmT, D, V);

  rope_cache_kernel<<<dim3(S), dim3(32), 0, stream>>>(cosb, sinb);
  embed_kernel<<<dim3(BS), dim3(256), 0, stream>>>(ids, emb, h);

  constexpr int ROPE_BLOCKS = (B * S * H * 32 + 255) / 256;

  for (int l = 0; l < L; ++l) {
    size_t DD = (size_t)D * D, DF = (size_t)D * F;
    size_t oDR = (size_t)l * D * R, oRD = (size_t)l * R * D;
    size_t oRF = (size_t)l * R * F, oFR = (size_t)l * F * R;

    // ---- attention block ----
    rmsnorm_bf16_kernel<<<dim3(BS), 256, 0, stream>>>(h, ln1 + (size_t)l * D, x_bf);
    gemmb(x_bf, wqkvT + (size_t)l * 3 * DD, qkv, BS, 3 * D, D, 1.0f, false, stream);
    { Ptr3 ap = {{aq + oDR, ak + oDR, av + oDR}};
      lora_xa_kernel<3><<<dim3(BS), 256, 0, stream>>>(x_bf, ap, t2, D);
      Ptr3 bp = {{bq + oRD, bk + oRD, bv + oRD}};
      lora_apply_kernel<3><<<dim3(3 * D / 256, BS), 256, 0, stream>>>(t2, bp, qkv, D, 10); }
    rope_apply_kernel<<<dim3(ROPE_BLOCKS), 256, 0, stream>>>(qkv, cosb, sinb, RS_QKV);
    rope_apply_kernel<<<dim3(ROPE_BLOCKS), 256, 0, stream>>>(qkv + D, cosb, sinb, RS_QKV);

    attn_mfma_kernel<<<dim3(B * H * (S / 64)), 256, 0, stream>>>(qkv, amask, obf);

    gemmb(obf, woT + l * DD, h, BS, D, D, 1.0f, true, stream);
    { Ptr3 ap = {{ao + oDR, nullptr, nullptr}};
      lora_xa_kernel<1><<<dim3(BS), 256, 0, stream>>>(obf, ap, t2, D);
      Ptr3 bp = {{bo + oRD, nullptr, nullptr}};
      lora_apply_kernel<1><<<dim3(D / 256, BS), 256, 0, stream>>>(t2, bp, h, D, 10); }

    // ---- MLP block ----
    rmsnorm_bf16_kernel<<<dim3(BS), 256, 0, stream>>>(h, ln2 + (size_t)l * D, x_bf);
    gemmb(x_bf, wguT + (size_t)l * 2 * DF, gu, BS, 2 * F, D, 1.0f, false, stream);
    { Ptr3 ap = {{ag + oDR, au + oDR, nullptr}};
      lora_xa_kernel<2><<<dim3(BS), 256, 0, stream>>>(x_bf, ap, t2, D);
      Ptr3 bp = {{bg + oRF, bu + oRF, nullptr}};
      lora_apply_kernel<2><<<dim3(2 * F / 256, BS), 256, 0, stream>>>(t2, bp, gu, F, 12); }

    silu_mul_kernel<<<dim3(BS * F / 256), 256, 0, stream>>>(gu, gbf);

    gemmb(gbf, wdT + l * DF, h, BS, D, F, 1.0f, true, stream);
    { Ptr3 ap = {{ad + oFR, nullptr, nullptr}};
      lora_xa_kernel<1><<<dim3(BS), 256, 0, stream>>>(gbf, ap, t2, F);
      Ptr3 bp = {{bd + oRD, nullptr, nullptr}};
      lora_apply_kernel<1><<<dim3(D / 256, BS), 256, 0, stream>>>(t2, bp, h, D, 10); }
  }

  // ---- final norm + heads ----
  rmsnorm_bf16_kernel<<<dim3(BS), 256, 0, stream>>>(h, final_ln, x_bf);
  gemmb(x_bf, lmT, logits, BS, V, D, 1.0f, false, stream);
  value_kernel<<<dim3(BS), 256, 0, stream>>>(x_bf, value_w, value_b, values);
}